// Round 3
// baseline (733.701 us; speedup 1.0000x reference)
//
#include <hip/hip_runtime.h>
#include <math.h>

#define I_DIM 256
#define O_DIM 2048
#define R_DIM 200000
#define K_SEL 2048
#define CAP   8192

// ---- workspace layout (offsets in u32 units) ----
#define WS_HIST   0         // u32[65536]
#define WS_META   65536     // u32[16]: [0]=B, [1]=tot, [2]=counter, [4]=norm f32
#define WS_CAND   65552     // u64[CAP] (16384 u32)
#define WS_IDX    81936     // i32[2048]
#define WS_SCALE  83984     // f32[2048]
#define WS_KEYS   86032     // u64[R] (400000 u32)
#define WS_RH     486032    // f32[I*O] (524288 u32)
#define WS_WXH    1010320   // f32[I*O] (524288 u32)
#define WS_X      1534608   // f32[I*O] (524288 u32)  x_topk in [k][j] layout

__device__ __forceinline__ unsigned sortable_key32(float f) {
    unsigned b = __float_as_uint(f);
    return (b & 0x80000000u) ? ~b : (b | 0x80000000u);
}
__device__ __forceinline__ float unsortable_key32(unsigned k) {
    unsigned b = (k & 0x80000000u) ? (k ^ 0x80000000u) : ~k;
    return __uint_as_float(b);
}

// K0: norm = fl32(sqrt(exact sum p^2)).
__global__ void norm_kernel(const float* __restrict__ p, float* __restrict__ norm_out) {
    if (threadIdx.x == 0) {
        double n = 0.0;
        for (int k = 0; k < I_DIM; k++) { double v = (double)p[k]; n += v * v; }
        norm_out[0] = (float)sqrt(n);
    }
}

// K1 v2: LDS-staged coalesced scoring.
// Old pattern: lane-per-row float4 loads -> 64 distinct cache lines per
// instruction (rows 1KB apart) -> MSHR/transaction-bound (~3x the 33us
// HBM floor). New: stage the block's 256 rows through LDS in 8 k-chunks
// of 32 (tile[256][36], 36KB); global loads are 128B-contiguous per 8
// lanes. Per-thread math is UNCHANGED: L[k%8] accumulators, k ascending,
// identical operands and association order -> bit-exact vs v1.
#define SH_KC 32
#define SH_PITCH 36   // +4 pad: 144B row pitch keeps 16B alignment for b128

__global__ void __launch_bounds__(256) score_hist_kernel(
    const float* __restrict__ embs, const float* __restrict__ p,
    const float* __restrict__ mask, const float* __restrict__ normp,
    unsigned long long* __restrict__ keys, unsigned* __restrict__ hist) {
    __shared__ float sp[I_DIM];
    __shared__ float tile[256][SH_PITCH];
    const int tid = threadIdx.x;
    if (tid < I_DIM) sp[tid] = p[tid];
    const int row0 = blockIdx.x * 256;
    const int r = row0 + tid;

    float L[8] = {0.f,0.f,0.f,0.f,0.f,0.f,0.f,0.f};

    for (int kc = 0; kc < I_DIM; kc += SH_KC) {
        __syncthreads();   // tile reuse guard (also covers sp on first pass)
        // stage: 2048 float4 = 256 rows x 8 float4; thread t, rep 0..7
        // handles flat float4 #(rep*256+t): row = f>>3, col4 = f&7 ->
        // lanes 8a..8a+7 read one contiguous 128B row piece.
        #pragma unroll
        for (int rep = 0; rep < 8; rep++) {
            const int f   = rep * 256 + tid;
            const int rr  = f >> 3;
            const int c4  = f & 7;
            int grow = row0 + rr;
            if (grow >= R_DIM) grow = R_DIM - 1;   // clamp: dup reads, emit skipped
            float4 v = *(const float4*)(embs + (size_t)grow * I_DIM + kc + c4 * 4);
            *(float4*)&tile[rr][c4 * 4] = v;
        }
        __syncthreads();
        // compute this k-chunk from LDS; acc index (k%8) = (4*i4 + t) & 7
        #pragma unroll
        for (int i4 = 0; i4 < 8; i4++) {
            float4 a  = *(const float4*)&tile[tid][i4 * 4];
            float4 qa = *(const float4*)&sp[kc + i4 * 4];
            const int base = (4 * i4) & 7;    // 0 or 4
            L[base + 0] = fmaf(a.x, qa.x, L[base + 0]);
            L[base + 1] = fmaf(a.y, qa.y, L[base + 1]);
            L[base + 2] = fmaf(a.z, qa.z, L[base + 2]);
            L[base + 3] = fmaf(a.w, qa.w, L[base + 3]);
        }
    }

    if (r >= R_DIM) return;
    float t0 = L[0] + L[4], t1 = L[1] + L[5], t2 = L[2] + L[6], t3 = L[3] + L[7];
    float d = (t0 + t1) + (t2 + t3);
    float s = d / normp[0] + mask[r];
    unsigned k32 = sortable_key32(s);
    keys[r] = ((unsigned long long)k32 << 32) |
              (unsigned long long)(~(unsigned)r);   // lower idx wins ties
    atomicAdd(&hist[k32 >> 16], 1u);
}

// K2: find threshold bin B (unchanged).
__global__ void __launch_bounds__(1024) find_thresh_kernel(
    const unsigned* __restrict__ hist, unsigned* __restrict__ meta) {
    __shared__ unsigned T[1024];
    const int t = threadIdx.x;
    const int base = t * 64;
    unsigned s = 0;
    for (int b = 0; b < 64; b++) s += hist[base + b];
    T[t] = s;
    __syncthreads();
    if (t == 0) {
        unsigned run = 0;
        int chunk = 1023;
        while (chunk >= 0 && run + T[chunk] < K_SEL) { run += T[chunk]; chunk--; }
        unsigned B = 0, tot = run;
        if (chunk >= 0) {
            unsigned r2 = run;
            for (int b = 63; b >= 0; b--) {
                unsigned c = hist[chunk * 64 + b];
                if (r2 + c >= K_SEL) { B = (unsigned)(chunk * 64 + b); tot = r2 + c; break; }
                r2 += c;
            }
        }
        meta[0] = B;
        meta[1] = tot;
    }
}

// K3: compact keys with bin >= B (unchanged).
__global__ void __launch_bounds__(256) compact_kernel(
    const unsigned long long* __restrict__ keys,
    const unsigned* __restrict__ meta, unsigned* __restrict__ counter,
    unsigned long long* __restrict__ cand) {
    const unsigned B = meta[0];
    int i0 = blockIdx.x * blockDim.x + threadIdx.x;
    int stride = gridDim.x * blockDim.x;
    for (int r = i0; r < R_DIM; r += stride) {
        unsigned long long key = keys[r];
        if ((unsigned)(key >> 48) >= B) {
            unsigned slot = atomicAdd(counter, 1u);
            if (slot < CAP) cand[slot] = key;
        }
    }
}

// K4: exact global rank (unchanged).
__global__ void __launch_bounds__(256) rank_emit_kernel(
    const unsigned long long* __restrict__ cand,
    const unsigned* __restrict__ counter,
    int* __restrict__ sel_idx, float* __restrict__ sel_scale) {
    unsigned n = *counter;
    if (n > CAP) n = CAP;
    unsigned s = blockIdx.x * blockDim.x + threadIdx.x;
    if (s >= n) return;
    unsigned long long k1 = cand[s];
    unsigned rank = 0;
    for (unsigned q = 0; q < n; q++) rank += (cand[q] > k1) ? 1u : 0u;
    if (rank < K_SEL) {
        unsigned idxv = ~(unsigned)(k1 & 0xFFFFFFFFull);
        sel_idx[rank]   = (int)idxv;
        sel_scale[rank] = tanhf(unsortable_key32((unsigned)(k1 >> 32)));
    }
}

// K5: materialize X[k][j] = embs[sel_idx[j]][k] * scale[j] (unchanged).
__global__ void __launch_bounds__(256) build_x_kernel(
    const float* __restrict__ embs, const int* __restrict__ sel_idx,
    const float* __restrict__ sel_scale, float* __restrict__ X) {
    const int j = blockIdx.x;
    const int row = sel_idx[j];
    const float sc = sel_scale[j];
    const int k = threadIdx.x;
    X[(size_t)k * O_DIM + j] = embs[(size_t)row * I_DIM + k] * sc;
}

// ==== GRU gates v4: scalar-pipe weights + pipelined vector streams ====
// Round-1 evidence: wave-uniform weight addresses compile to s_load
// (scalar cache, scalar pipe -- costs neither VALU nor LDS cycles).
// Round-2 evidence: KG-deep register rotation keeps ~16 X/h loads in
// flight, fixing the serialization that sank round 1. Round 2's LDS
// weight broadcasts (5 ds_read_b128 per k per thread ~= 15K LDS-pipe
// cyc/wave vs 10K FMA cyc) were the new bottleneck. v4 = s_load weights
// + KG rotation, zero LDS. FMA order per accumulator unchanged (k asc).
#define TI 4
#define KG 8

__global__ void __launch_bounds__(256) gate_ur_kernel(
    const float* __restrict__ X, const float* __restrict__ history,
    const float* __restrict__ Wu, const float* __restrict__ Uu,
    const float* __restrict__ bu,
    const float* __restrict__ Wr, const float* __restrict__ Ur,
    const float* __restrict__ br,
    const float* __restrict__ Wh,
    float* __restrict__ u_out, float* __restrict__ rh,
    float* __restrict__ wxh) {
    const int j  = blockIdx.x * 256 + threadIdx.x;
    const int i0 = blockIdx.y * TI;

    // wave-uniform weight row pointers -> scalar loads
    const float* wu0 = Wu + (size_t)i0 * I_DIM; const float* wu1 = wu0 + I_DIM;
    const float* wu2 = wu1 + I_DIM;             const float* wu3 = wu2 + I_DIM;
    const float* uu0 = Uu + (size_t)i0 * I_DIM; const float* uu1 = uu0 + I_DIM;
    const float* uu2 = uu1 + I_DIM;             const float* uu3 = uu2 + I_DIM;
    const float* wr0 = Wr + (size_t)i0 * I_DIM; const float* wr1 = wr0 + I_DIM;
    const float* wr2 = wr1 + I_DIM;             const float* wr3 = wr2 + I_DIM;
    const float* ur0 = Ur + (size_t)i0 * I_DIM; const float* ur1 = ur0 + I_DIM;
    const float* ur2 = ur1 + I_DIM;             const float* ur3 = ur2 + I_DIM;
    const float* wh0 = Wh + (size_t)i0 * I_DIM; const float* wh1 = wh0 + I_DIM;
    const float* wh2 = wh1 + I_DIM;             const float* wh3 = wh2 + I_DIM;

    const float* Xp = X + j;
    const float* Hp = history + j;

    float acc[5][TI];
    #pragma unroll
    for (int m = 0; m < 5; m++)
        #pragma unroll
        for (int ii = 0; ii < TI; ii++) acc[m][ii] = 0.f;

    float xbuf[KG], hbuf[KG];
    #pragma unroll
    for (int t = 0; t < KG; t++) {
        xbuf[t] = Xp[(size_t)t * O_DIM];
        hbuf[t] = Hp[(size_t)t * O_DIM];
    }

    for (int k0 = 0; k0 < I_DIM; k0 += KG) {
        const int kn = (k0 + KG < I_DIM) ? (k0 + KG) : 0;
        float xn[KG], hn[KG];
        #pragma unroll
        for (int t = 0; t < KG; t++) {
            xn[t] = Xp[(size_t)(kn + t) * O_DIM];
            hn[t] = Hp[(size_t)(kn + t) * O_DIM];
        }
        #pragma unroll
        for (int t = 0; t < KG; t++) {
            const int k = k0 + t;
            const float xv = xbuf[t];
            const float hv = hbuf[t];
            acc[0][0] = fmaf(wu0[k], xv, acc[0][0]);
            acc[0][1] = fmaf(wu1[k], xv, acc[0][1]);
            acc[0][2] = fmaf(wu2[k], xv, acc[0][2]);
            acc[0][3] = fmaf(wu3[k], xv, acc[0][3]);
            acc[1][0] = fmaf(uu0[k], hv, acc[1][0]);
            acc[1][1] = fmaf(uu1[k], hv, acc[1][1]);
            acc[1][2] = fmaf(uu2[k], hv, acc[1][2]);
            acc[1][3] = fmaf(uu3[k], hv, acc[1][3]);
            acc[2][0] = fmaf(wr0[k], xv, acc[2][0]);
            acc[2][1] = fmaf(wr1[k], xv, acc[2][1]);
            acc[2][2] = fmaf(wr2[k], xv, acc[2][2]);
            acc[2][3] = fmaf(wr3[k], xv, acc[2][3]);
            acc[3][0] = fmaf(ur0[k], hv, acc[3][0]);
            acc[3][1] = fmaf(ur1[k], hv, acc[3][1]);
            acc[3][2] = fmaf(ur2[k], hv, acc[3][2]);
            acc[3][3] = fmaf(ur3[k], hv, acc[3][3]);
            acc[4][0] = fmaf(wh0[k], xv, acc[4][0]);
            acc[4][1] = fmaf(wh1[k], xv, acc[4][1]);
            acc[4][2] = fmaf(wh2[k], xv, acc[4][2]);
            acc[4][3] = fmaf(wh3[k], xv, acc[4][3]);
        }
        #pragma unroll
        for (int t = 0; t < KG; t++) { xbuf[t] = xn[t]; hbuf[t] = hn[t]; }
    }

    #pragma unroll
    for (int ii = 0; ii < TI; ii++) {
        const size_t o = (size_t)(i0 + ii) * O_DIM + j;
        float uz = acc[0][ii] + acc[1][ii] + bu[o];
        float rz = acc[2][ii] + acc[3][ii] + br[o];
        float ug = 1.f / (1.f + expf(-uz));
        float rg = 1.f / (1.f + expf(-rz));
        u_out[o] = ug;
        rh[o]    = rg * history[o];
        wxh[o]   = acc[4][ii];
    }
}

#define KGH 16

__global__ void __launch_bounds__(256) gate_h_kernel(
    const float* __restrict__ history, const float* __restrict__ Uh,
    const float* __restrict__ bh,
    const float* __restrict__ u_out, const float* __restrict__ rh,
    const float* __restrict__ wxh, float* __restrict__ out) {
    const int j  = blockIdx.x * 256 + threadIdx.x;
    const int i0 = blockIdx.y * TI;

    const float* uh0 = Uh + (size_t)i0 * I_DIM; const float* uh1 = uh0 + I_DIM;
    const float* uh2 = uh1 + I_DIM;             const float* uh3 = uh2 + I_DIM;

    const float* Rp = rh + j;

    float acc[TI] = {0.f, 0.f, 0.f, 0.f};
    float rbuf[KGH];
    #pragma unroll
    for (int t = 0; t < KGH; t++) rbuf[t] = Rp[(size_t)t * O_DIM];

    for (int k0 = 0; k0 < I_DIM; k0 += KGH) {
        const int kn = (k0 + KGH < I_DIM) ? (k0 + KGH) : 0;
        float rn[KGH];
        #pragma unroll
        for (int t = 0; t < KGH; t++) rn[t] = Rp[(size_t)(kn + t) * O_DIM];
        #pragma unroll
        for (int t = 0; t < KGH; t++) {
            const int k = k0 + t;
            const float rv = rbuf[t];
            acc[0] = fmaf(uh0[k], rv, acc[0]);
            acc[1] = fmaf(uh1[k], rv, acc[1]);
            acc[2] = fmaf(uh2[k], rv, acc[2]);
            acc[3] = fmaf(uh3[k], rv, acc[3]);
        }
        #pragma unroll
        for (int t = 0; t < KGH; t++) rbuf[t] = rn[t];
    }

    #pragma unroll
    for (int ii = 0; ii < TI; ii++) {
        const size_t o = (size_t)(i0 + ii) * O_DIM + j;
        float hcap = tanhf(wxh[o] + acc[ii] + bh[o]);
        float ug = u_out[o];
        out[o] = (1.f - ug) * history[o] + ug * hcap;
    }
}

extern "C" void kernel_launch(void* const* d_in, const int* in_sizes, int n_in,
                              void* d_out, int out_size, void* d_ws, size_t ws_size,
                              hipStream_t stream) {
    const float* embs    = (const float*)d_in[0];
    const float* history = (const float*)d_in[1];
    const float* mask    = (const float*)d_in[2];
    const float* p       = (const float*)d_in[3];
    const float* Wu      = (const float*)d_in[4];
    const float* Uu      = (const float*)d_in[5];
    const float* bu      = (const float*)d_in[6];
    const float* Wr      = (const float*)d_in[7];
    const float* Ur      = (const float*)d_in[8];
    const float* br      = (const float*)d_in[9];
    const float* Wh      = (const float*)d_in[10];
    const float* Uh      = (const float*)d_in[11];
    const float* bh      = (const float*)d_in[12];
    float* out = (float*)d_out;

    unsigned* ws = (unsigned*)d_ws;
    unsigned* hist = ws + WS_HIST;
    unsigned* meta = ws + WS_META;
    unsigned long long* cand = (unsigned long long*)(ws + WS_CAND);
    int* sel_idx     = (int*)(ws + WS_IDX);
    float* sel_scale = (float*)(ws + WS_SCALE);
    unsigned long long* keys = (unsigned long long*)(ws + WS_KEYS);
    float* rh  = (float*)(ws + WS_RH);
    float* wxh = (float*)(ws + WS_WXH);
    float* X   = (float*)(ws + WS_X);
    float* normp = (float*)(meta + 4);

    hipMemsetAsync(ws, 0, (size_t)(WS_META + 16) * sizeof(unsigned), stream);

    hipLaunchKernelGGL(norm_kernel, dim3(1), dim3(64), 0, stream, p, normp);
    hipLaunchKernelGGL(score_hist_kernel, dim3((R_DIM + 255) / 256), dim3(256), 0, stream,
                       embs, p, mask, normp, keys, hist);
    hipLaunchKernelGGL(find_thresh_kernel, dim3(1), dim3(1024), 0, stream,
                       hist, meta);
    hipLaunchKernelGGL(compact_kernel, dim3(512), dim3(256), 0, stream,
                       keys, meta, meta + 2, cand);
    hipLaunchKernelGGL(rank_emit_kernel, dim3(CAP / 256), dim3(256), 0, stream,
                       cand, meta + 2, sel_idx, sel_scale);
    hipLaunchKernelGGL(build_x_kernel, dim3(K_SEL), dim3(256), 0, stream,
                       embs, sel_idx, sel_scale, X);
    hipLaunchKernelGGL(gate_ur_kernel, dim3(O_DIM / 256, I_DIM / TI), dim3(256), 0, stream,
                       X, history, Wu, Uu, bu, Wr, Ur, br, Wh,
                       out /*u*/, rh, wxh);
    hipLaunchKernelGGL(gate_h_kernel, dim3(O_DIM / 256, I_DIM / TI), dim3(256), 0, stream,
                       history, Uh, bh, out /*u*/, rh, wxh, out);
}

// Round 4
// 694.256 us; speedup vs baseline: 1.0568x; 1.0568x over previous
//
#include <hip/hip_runtime.h>
#include <math.h>

#define I_DIM 256
#define O_DIM 2048
#define R_DIM 200000
#define K_SEL 2048
#define CAP   8192

// ---- workspace layout (offsets in u32 units) ----
#define WS_HIST   0         // u32[65536]
#define WS_META   65536     // u32[16]: [0]=B, [1]=tot, [2]=counter, [4]=norm f32
#define WS_CAND   65552     // u64[CAP] (16384 u32)
#define WS_IDX    81936     // i32[2048]
#define WS_SCALE  83984     // f32[2048]
#define WS_KEYS   86032     // u64[R] (400000 u32)
#define WS_RH     486032    // f32[I*O] (524288 u32)
#define WS_WXH    1010320   // f32[I*O] (524288 u32)
#define WS_X      1534608   // f32[I*O] (524288 u32)  x_topk in [k][j] layout

__device__ __forceinline__ unsigned sortable_key32(float f) {
    unsigned b = __float_as_uint(f);
    return (b & 0x80000000u) ? ~b : (b | 0x80000000u);
}
__device__ __forceinline__ float unsortable_key32(unsigned k) {
    unsigned b = (k & 0x80000000u) ? (k ^ 0x80000000u) : ~k;
    return __uint_as_float(b);
}

// K0: norm = fl32(sqrt(exact sum p^2)).
__global__ void norm_kernel(const float* __restrict__ p, float* __restrict__ norm_out) {
    if (threadIdx.x == 0) {
        double n = 0.0;
        for (int k = 0; k < I_DIM; k++) { double v = (double)p[k]; n += v * v; }
        norm_out[0] = (float)sqrt(n);
    }
}

// K1 v3: direct loads + register-rotation prefetch (the structure that fixed
// the gates in round 2). Round-3 LDS staging was a 2x regression: VGPR=240,
// occupancy 9.4%, barrier-serialized (reuse factor of embs is 1 -> LDS buys
// nothing). v3 = v1's lane-per-row pattern, but pipelined: groups of 4
// float4-pairs, prefetch group g+1 into named regs while FMA-ing group g.
// ~8 outstanding 16B loads/lane at VGPR~110 -> 16 waves/CU -> BW-paced.
// FMA order per accumulator identical to v1/v2 (pair index ascending):
// bit-exact OpenBLAS sgemv_t emulation preserved.
#define PF_G 4

__global__ void __launch_bounds__(256) score_hist_kernel(
    const float* __restrict__ embs, const float* __restrict__ p,
    const float* __restrict__ mask, const float* __restrict__ normp,
    unsigned long long* __restrict__ keys, unsigned* __restrict__ hist) {
    __shared__ float sp[I_DIM];
    if (threadIdx.x < I_DIM) sp[threadIdx.x] = p[threadIdx.x];
    __syncthreads();
    const int r = blockIdx.x * 256 + threadIdx.x;
    if (r >= R_DIM) return;
    const float4* e4 = (const float4*)(embs + (size_t)r * I_DIM);
    const float4* p4 = (const float4*)sp;

    float L[8] = {0.f,0.f,0.f,0.f,0.f,0.f,0.f,0.f};
    float4 ca[PF_G], cb[PF_G], na[PF_G], nb[PF_G];
    #pragma unroll
    for (int t = 0; t < PF_G; t++) { ca[t] = e4[2*t]; cb[t] = e4[2*t+1]; }

    for (int g0 = 0; g0 < 32; g0 += PF_G) {
        const int gn = (g0 + PF_G < 32) ? (g0 + PF_G) : 0;  // dummy wrap last iter
        #pragma unroll
        for (int t = 0; t < PF_G; t++) {
            na[t] = e4[2*(gn+t)];
            nb[t] = e4[2*(gn+t)+1];
        }
        #pragma unroll
        for (int t = 0; t < PF_G; t++) {
            const int i = g0 + t;
            float4 qa = p4[2*i], qb = p4[2*i+1];
            L[0] = fmaf(ca[t].x, qa.x, L[0]);
            L[1] = fmaf(ca[t].y, qa.y, L[1]);
            L[2] = fmaf(ca[t].z, qa.z, L[2]);
            L[3] = fmaf(ca[t].w, qa.w, L[3]);
            L[4] = fmaf(cb[t].x, qb.x, L[4]);
            L[5] = fmaf(cb[t].y, qb.y, L[5]);
            L[6] = fmaf(cb[t].z, qb.z, L[6]);
            L[7] = fmaf(cb[t].w, qb.w, L[7]);
        }
        #pragma unroll
        for (int t = 0; t < PF_G; t++) { ca[t] = na[t]; cb[t] = nb[t]; }
    }

    float t0 = L[0] + L[4], t1 = L[1] + L[5], t2 = L[2] + L[6], t3 = L[3] + L[7];
    float d = (t0 + t1) + (t2 + t3);
    float s = d / normp[0] + mask[r];
    unsigned k32 = sortable_key32(s);
    keys[r] = ((unsigned long long)k32 << 32) |
              (unsigned long long)(~(unsigned)r);   // lower idx wins ties
    atomicAdd(&hist[k32 >> 16], 1u);
}

// K2: find threshold bin B (unchanged).
__global__ void __launch_bounds__(1024) find_thresh_kernel(
    const unsigned* __restrict__ hist, unsigned* __restrict__ meta) {
    __shared__ unsigned T[1024];
    const int t = threadIdx.x;
    const int base = t * 64;
    unsigned s = 0;
    for (int b = 0; b < 64; b++) s += hist[base + b];
    T[t] = s;
    __syncthreads();
    if (t == 0) {
        unsigned run = 0;
        int chunk = 1023;
        while (chunk >= 0 && run + T[chunk] < K_SEL) { run += T[chunk]; chunk--; }
        unsigned B = 0, tot = run;
        if (chunk >= 0) {
            unsigned r2 = run;
            for (int b = 63; b >= 0; b--) {
                unsigned c = hist[chunk * 64 + b];
                if (r2 + c >= K_SEL) { B = (unsigned)(chunk * 64 + b); tot = r2 + c; break; }
                r2 += c;
            }
        }
        meta[0] = B;
        meta[1] = tot;
    }
}

// K3: compact keys with bin >= B (unchanged).
__global__ void __launch_bounds__(256) compact_kernel(
    const unsigned long long* __restrict__ keys,
    const unsigned* __restrict__ meta, unsigned* __restrict__ counter,
    unsigned long long* __restrict__ cand) {
    const unsigned B = meta[0];
    int i0 = blockIdx.x * blockDim.x + threadIdx.x;
    int stride = gridDim.x * blockDim.x;
    for (int r = i0; r < R_DIM; r += stride) {
        unsigned long long key = keys[r];
        if ((unsigned)(key >> 48) >= B) {
            unsigned slot = atomicAdd(counter, 1u);
            if (slot < CAP) cand[slot] = key;
        }
    }
}

// K4: exact global rank (unchanged).
__global__ void __launch_bounds__(256) rank_emit_kernel(
    const unsigned long long* __restrict__ cand,
    const unsigned* __restrict__ counter,
    int* __restrict__ sel_idx, float* __restrict__ sel_scale) {
    unsigned n = *counter;
    if (n > CAP) n = CAP;
    unsigned s = blockIdx.x * blockDim.x + threadIdx.x;
    if (s >= n) return;
    unsigned long long k1 = cand[s];
    unsigned rank = 0;
    for (unsigned q = 0; q < n; q++) rank += (cand[q] > k1) ? 1u : 0u;
    if (rank < K_SEL) {
        unsigned idxv = ~(unsigned)(k1 & 0xFFFFFFFFull);
        sel_idx[rank]   = (int)idxv;
        sel_scale[rank] = tanhf(unsortable_key32((unsigned)(k1 >> 32)));
    }
}

// K5: materialize X[k][j] = embs[sel_idx[j]][k] * scale[j] (unchanged).
__global__ void __launch_bounds__(256) build_x_kernel(
    const float* __restrict__ embs, const int* __restrict__ sel_idx,
    const float* __restrict__ sel_scale, float* __restrict__ X) {
    const int j = blockIdx.x;
    const int row = sel_idx[j];
    const float sc = sel_scale[j];
    const int k = threadIdx.x;
    X[(size_t)k * O_DIM + j] = embs[(size_t)row * I_DIM + k] * sc;
}

// ==== GRU gates v4 (unchanged from round 3): scalar-pipe weights +
// pipelined vector streams. Times not yet visible in top-5; will optimize
// with counter evidence once score_hist drops below them. ====
#define TI 4
#define KG 8

__global__ void __launch_bounds__(256) gate_ur_kernel(
    const float* __restrict__ X, const float* __restrict__ history,
    const float* __restrict__ Wu, const float* __restrict__ Uu,
    const float* __restrict__ bu,
    const float* __restrict__ Wr, const float* __restrict__ Ur,
    const float* __restrict__ br,
    const float* __restrict__ Wh,
    float* __restrict__ u_out, float* __restrict__ rh,
    float* __restrict__ wxh) {
    const int j  = blockIdx.x * 256 + threadIdx.x;
    const int i0 = blockIdx.y * TI;

    const float* wu0 = Wu + (size_t)i0 * I_DIM; const float* wu1 = wu0 + I_DIM;
    const float* wu2 = wu1 + I_DIM;             const float* wu3 = wu2 + I_DIM;
    const float* uu0 = Uu + (size_t)i0 * I_DIM; const float* uu1 = uu0 + I_DIM;
    const float* uu2 = uu1 + I_DIM;             const float* uu3 = uu2 + I_DIM;
    const float* wr0 = Wr + (size_t)i0 * I_DIM; const float* wr1 = wr0 + I_DIM;
    const float* wr2 = wr1 + I_DIM;             const float* wr3 = wr2 + I_DIM;
    const float* ur0 = Ur + (size_t)i0 * I_DIM; const float* ur1 = ur0 + I_DIM;
    const float* ur2 = ur1 + I_DIM;             const float* ur3 = ur2 + I_DIM;
    const float* wh0 = Wh + (size_t)i0 * I_DIM; const float* wh1 = wh0 + I_DIM;
    const float* wh2 = wh1 + I_DIM;             const float* wh3 = wh2 + I_DIM;

    const float* Xp = X + j;
    const float* Hp = history + j;

    float acc[5][TI];
    #pragma unroll
    for (int m = 0; m < 5; m++)
        #pragma unroll
        for (int ii = 0; ii < TI; ii++) acc[m][ii] = 0.f;

    float xbuf[KG], hbuf[KG];
    #pragma unroll
    for (int t = 0; t < KG; t++) {
        xbuf[t] = Xp[(size_t)t * O_DIM];
        hbuf[t] = Hp[(size_t)t * O_DIM];
    }

    for (int k0 = 0; k0 < I_DIM; k0 += KG) {
        const int kn = (k0 + KG < I_DIM) ? (k0 + KG) : 0;
        float xn[KG], hn[KG];
        #pragma unroll
        for (int t = 0; t < KG; t++) {
            xn[t] = Xp[(size_t)(kn + t) * O_DIM];
            hn[t] = Hp[(size_t)(kn + t) * O_DIM];
        }
        #pragma unroll
        for (int t = 0; t < KG; t++) {
            const int k = k0 + t;
            const float xv = xbuf[t];
            const float hv = hbuf[t];
            acc[0][0] = fmaf(wu0[k], xv, acc[0][0]);
            acc[0][1] = fmaf(wu1[k], xv, acc[0][1]);
            acc[0][2] = fmaf(wu2[k], xv, acc[0][2]);
            acc[0][3] = fmaf(wu3[k], xv, acc[0][3]);
            acc[1][0] = fmaf(uu0[k], hv, acc[1][0]);
            acc[1][1] = fmaf(uu1[k], hv, acc[1][1]);
            acc[1][2] = fmaf(uu2[k], hv, acc[1][2]);
            acc[1][3] = fmaf(uu3[k], hv, acc[1][3]);
            acc[2][0] = fmaf(wr0[k], xv, acc[2][0]);
            acc[2][1] = fmaf(wr1[k], xv, acc[2][1]);
            acc[2][2] = fmaf(wr2[k], xv, acc[2][2]);
            acc[2][3] = fmaf(wr3[k], xv, acc[2][3]);
            acc[3][0] = fmaf(ur0[k], hv, acc[3][0]);
            acc[3][1] = fmaf(ur1[k], hv, acc[3][1]);
            acc[3][2] = fmaf(ur2[k], hv, acc[3][2]);
            acc[3][3] = fmaf(ur3[k], hv, acc[3][3]);
            acc[4][0] = fmaf(wh0[k], xv, acc[4][0]);
            acc[4][1] = fmaf(wh1[k], xv, acc[4][1]);
            acc[4][2] = fmaf(wh2[k], xv, acc[4][2]);
            acc[4][3] = fmaf(wh3[k], xv, acc[4][3]);
        }
        #pragma unroll
        for (int t = 0; t < KG; t++) { xbuf[t] = xn[t]; hbuf[t] = hn[t]; }
    }

    #pragma unroll
    for (int ii = 0; ii < TI; ii++) {
        const size_t o = (size_t)(i0 + ii) * O_DIM + j;
        float uz = acc[0][ii] + acc[1][ii] + bu[o];
        float rz = acc[2][ii] + acc[3][ii] + br[o];
        float ug = 1.f / (1.f + expf(-uz));
        float rg = 1.f / (1.f + expf(-rz));
        u_out[o] = ug;
        rh[o]    = rg * history[o];
        wxh[o]   = acc[4][ii];
    }
}

#define KGH 16

__global__ void __launch_bounds__(256) gate_h_kernel(
    const float* __restrict__ history, const float* __restrict__ Uh,
    const float* __restrict__ bh,
    const float* __restrict__ u_out, const float* __restrict__ rh,
    const float* __restrict__ wxh, float* __restrict__ out) {
    const int j  = blockIdx.x * 256 + threadIdx.x;
    const int i0 = blockIdx.y * TI;

    const float* uh0 = Uh + (size_t)i0 * I_DIM; const float* uh1 = uh0 + I_DIM;
    const float* uh2 = uh1 + I_DIM;             const float* uh3 = uh2 + I_DIM;

    const float* Rp = rh + j;

    float acc[TI] = {0.f, 0.f, 0.f, 0.f};
    float rbuf[KGH];
    #pragma unroll
    for (int t = 0; t < KGH; t++) rbuf[t] = Rp[(size_t)t * O_DIM];

    for (int k0 = 0; k0 < I_DIM; k0 += KGH) {
        const int kn = (k0 + KGH < I_DIM) ? (k0 + KGH) : 0;
        float rn[KGH];
        #pragma unroll
        for (int t = 0; t < KGH; t++) rn[t] = Rp[(size_t)(kn + t) * O_DIM];
        #pragma unroll
        for (int t = 0; t < KGH; t++) {
            const int k = k0 + t;
            const float rv = rbuf[t];
            acc[0] = fmaf(uh0[k], rv, acc[0]);
            acc[1] = fmaf(uh1[k], rv, acc[1]);
            acc[2] = fmaf(uh2[k], rv, acc[2]);
            acc[3] = fmaf(uh3[k], rv, acc[3]);
        }
        #pragma unroll
        for (int t = 0; t < KGH; t++) rbuf[t] = rn[t];
    }

    #pragma unroll
    for (int ii = 0; ii < TI; ii++) {
        const size_t o = (size_t)(i0 + ii) * O_DIM + j;
        float hcap = tanhf(wxh[o] + acc[ii] + bh[o]);
        float ug = u_out[o];
        out[o] = (1.f - ug) * history[o] + ug * hcap;
    }
}

extern "C" void kernel_launch(void* const* d_in, const int* in_sizes, int n_in,
                              void* d_out, int out_size, void* d_ws, size_t ws_size,
                              hipStream_t stream) {
    const float* embs    = (const float*)d_in[0];
    const float* history = (const float*)d_in[1];
    const float* mask    = (const float*)d_in[2];
    const float* p       = (const float*)d_in[3];
    const float* Wu      = (const float*)d_in[4];
    const float* Uu      = (const float*)d_in[5];
    const float* bu      = (const float*)d_in[6];
    const float* Wr      = (const float*)d_in[7];
    const float* Ur      = (const float*)d_in[8];
    const float* br      = (const float*)d_in[9];
    const float* Wh      = (const float*)d_in[10];
    const float* Uh      = (const float*)d_in[11];
    const float* bh      = (const float*)d_in[12];
    float* out = (float*)d_out;

    unsigned* ws = (unsigned*)d_ws;
    unsigned* hist = ws + WS_HIST;
    unsigned* meta = ws + WS_META;
    unsigned long long* cand = (unsigned long long*)(ws + WS_CAND);
    int* sel_idx     = (int*)(ws + WS_IDX);
    float* sel_scale = (float*)(ws + WS_SCALE);
    unsigned long long* keys = (unsigned long long*)(ws + WS_KEYS);
    float* rh  = (float*)(ws + WS_RH);
    float* wxh = (float*)(ws + WS_WXH);
    float* X   = (float*)(ws + WS_X);
    float* normp = (float*)(meta + 4);

    hipMemsetAsync(ws, 0, (size_t)(WS_META + 16) * sizeof(unsigned), stream);

    hipLaunchKernelGGL(norm_kernel, dim3(1), dim3(64), 0, stream, p, normp);
    hipLaunchKernelGGL(score_hist_kernel, dim3((R_DIM + 255) / 256), dim3(256), 0, stream,
                       embs, p, mask, normp, keys, hist);
    hipLaunchKernelGGL(find_thresh_kernel, dim3(1), dim3(1024), 0, stream,
                       hist, meta);
    hipLaunchKernelGGL(compact_kernel, dim3(512), dim3(256), 0, stream,
                       keys, meta, meta + 2, cand);
    hipLaunchKernelGGL(rank_emit_kernel, dim3(CAP / 256), dim3(256), 0, stream,
                       cand, meta + 2, sel_idx, sel_scale);
    hipLaunchKernelGGL(build_x_kernel, dim3(K_SEL), dim3(256), 0, stream,
                       embs, sel_idx, sel_scale, X);
    hipLaunchKernelGGL(gate_ur_kernel, dim3(O_DIM / 256, I_DIM / TI), dim3(256), 0, stream,
                       X, history, Wu, Uu, bu, Wr, Ur, br, Wh,
                       out /*u*/, rh, wxh);
    hipLaunchKernelGGL(gate_h_kernel, dim3(O_DIM / 256, I_DIM / TI), dim3(256), 0, stream,
                       history, Uh, bh, out /*u*/, rh, wxh, out);
}

// Round 5
// 634.843 us; speedup vs baseline: 1.1557x; 1.0936x over previous
//
#include <hip/hip_runtime.h>
#include <math.h>

#define I_DIM 256
#define O_DIM 2048
#define R_DIM 200000
#define K_SEL 2048
#define CAP   8192

// ---- workspace layout (offsets in u32 units) ----
#define WS_HIST   0         // u32[65536]
#define WS_META   65536     // u32[16]: [0]=B, [1]=tot, [2]=counter, [4]=norm f32
#define WS_CAND   65552     // u64[CAP] (16384 u32)
#define WS_IDX    81936     // i32[2048]
#define WS_SCALE  83984     // f32[2048]
#define WS_KEYS   86032     // u64[R] (400000 u32)
#define WS_RH     486032    // f32[I*O] (524288 u32)
#define WS_WXH    1010320   // f32[I*O] (524288 u32)
#define WS_X      1534608   // f32[I*O] (524288 u32)  x_topk in [k][j] layout

typedef unsigned int u32;
typedef __attribute__((address_space(1))) u32 gu32;
typedef __attribute__((address_space(3))) u32 lu32;

// Direct HBM->LDS DMA: no VGPR staging, cannot be collapsed by the compiler.
// LDS dest = wave-uniform base + lane*size (HW rule); global addr is per-lane.
static __device__ __forceinline__ void gload_lds16(const float* g, float* l) {
    __builtin_amdgcn_global_load_lds((const gu32*)g, (lu32*)l, 16, 0, 0);
}
static __device__ __forceinline__ void gload_lds4(const float* g, float* l) {
    __builtin_amdgcn_global_load_lds((const gu32*)g, (lu32*)l, 4, 0, 0);
}
#define WAIT_VM0()   do { asm volatile("s_waitcnt vmcnt(0)" ::: "memory"); \
                          __builtin_amdgcn_sched_barrier(0); } while (0)
#define WAIT_LGKM0() do { asm volatile("s_waitcnt lgkmcnt(0)" ::: "memory"); } while (0)

__device__ __forceinline__ unsigned sortable_key32(float f) {
    unsigned b = __float_as_uint(f);
    return (b & 0x80000000u) ? ~b : (b | 0x80000000u);
}
__device__ __forceinline__ float unsortable_key32(unsigned k) {
    unsigned b = (k & 0x80000000u) ? (k ^ 0x80000000u) : ~k;
    return __uint_as_float(b);
}

// K0: norm = fl32(sqrt(exact sum p^2)).
__global__ void norm_kernel(const float* __restrict__ p, float* __restrict__ norm_out) {
    if (threadIdx.x == 0) {
        double n = 0.0;
        for (int k = 0; k < I_DIM; k++) { double v = (double)p[k]; n += v * v; }
        norm_out[0] = (float)sqrt(n);
    }
}

// K1 v4: global_load_lds staging into WAVE-PRIVATE LDS (no barriers, no
// VGPR round-trip -- the two failure modes of rounds 3/4). Per k-chunk of
// 32 floats: 8 DMA instructions, each staging 8 rows x 128B coalesced.
// XOR swizzle (slot ^= row&7) applied at the global SOURCE and the LDS
// READ (both-sides rule): b128 reads then tile all 32 banks at the 1KB/wave
// minimum -> conflict-free. Compute mapping identical to round-3's
// correctness-validated version: acc (4*i4+c)&7, k ascending -> bit-exact
// OpenBLAS sgemv_t emulation preserved.
__global__ void __launch_bounds__(256) score_hist_kernel(
    const float* __restrict__ embs, const float* __restrict__ p,
    const float* __restrict__ mask, const float* __restrict__ normp,
    unsigned long long* __restrict__ keys, unsigned* __restrict__ hist) {
    __shared__ __align__(16) float sp[I_DIM];
    __shared__ __align__(16) float tile[4][64][32];   // 8KB per wave, private
    const int tid  = threadIdx.x;
    const int w    = tid >> 6;
    const int lane = tid & 63;
    if (tid < I_DIM) sp[tid] = p[tid];
    __syncthreads();                       // sp ready (only barrier)

    const int r = blockIdx.x * 256 + tid;  // this thread's row
    if (r >= R_DIM) return;                // whole waves exit together here

    const int row0 = blockIdx.x * 256 + w * 64;        // wave's first row
    const int c4   = (lane & 7) ^ (lane >> 3);         // pre-swizzled part

    float L[8] = {0.f,0.f,0.f,0.f,0.f,0.f,0.f,0.f};

    for (int m = 0; m < 8; m++) {
        WAIT_LGKM0();                      // prior chunk's ds_reads landed
        #pragma unroll
        for (int a = 0; a < 8; a++) {      // instr a stages rows 8a..8a+7
            int grow = row0 + 8 * a + (lane >> 3);
            if (grow >= R_DIM) grow = R_DIM - 1;       // dup read, emit-guarded
            gload_lds16(embs + (size_t)grow * I_DIM + m * 32 + c4 * 4,
                        &tile[w][a * 8][0]);
        }
        WAIT_VM0();
        #pragma unroll
        for (int i4 = 0; i4 < 8; i4++) {
            const int slot = i4 ^ (lane & 7);          // read-side swizzle
            float4 a4 = *(const float4*)&tile[w][lane][slot * 4];
            float4 q  = *(const float4*)&sp[m * 32 + i4 * 4];
            const int base = (4 * i4) & 7;             // 0 or 4
            L[base + 0] = fmaf(a4.x, q.x, L[base + 0]);
            L[base + 1] = fmaf(a4.y, q.y, L[base + 1]);
            L[base + 2] = fmaf(a4.z, q.z, L[base + 2]);
            L[base + 3] = fmaf(a4.w, q.w, L[base + 3]);
        }
    }

    float t0 = L[0] + L[4], t1 = L[1] + L[5], t2 = L[2] + L[6], t3 = L[3] + L[7];
    float d = (t0 + t1) + (t2 + t3);
    float s = d / normp[0] + mask[r];
    unsigned k32 = sortable_key32(s);
    keys[r] = ((unsigned long long)k32 << 32) |
              (unsigned long long)(~(unsigned)r);   // lower idx wins ties
    atomicAdd(&hist[k32 >> 16], 1u);
}

// K2: find threshold bin B (unchanged).
__global__ void __launch_bounds__(1024) find_thresh_kernel(
    const unsigned* __restrict__ hist, unsigned* __restrict__ meta) {
    __shared__ unsigned T[1024];
    const int t = threadIdx.x;
    const int base = t * 64;
    unsigned s = 0;
    for (int b = 0; b < 64; b++) s += hist[base + b];
    T[t] = s;
    __syncthreads();
    if (t == 0) {
        unsigned run = 0;
        int chunk = 1023;
        while (chunk >= 0 && run + T[chunk] < K_SEL) { run += T[chunk]; chunk--; }
        unsigned B = 0, tot = run;
        if (chunk >= 0) {
            unsigned r2 = run;
            for (int b = 63; b >= 0; b--) {
                unsigned c = hist[chunk * 64 + b];
                if (r2 + c >= K_SEL) { B = (unsigned)(chunk * 64 + b); tot = r2 + c; break; }
                r2 += c;
            }
        }
        meta[0] = B;
        meta[1] = tot;
    }
}

// K3: compact keys with bin >= B (unchanged).
__global__ void __launch_bounds__(256) compact_kernel(
    const unsigned long long* __restrict__ keys,
    const unsigned* __restrict__ meta, unsigned* __restrict__ counter,
    unsigned long long* __restrict__ cand) {
    const unsigned B = meta[0];
    int i0 = blockIdx.x * blockDim.x + threadIdx.x;
    int stride = gridDim.x * blockDim.x;
    for (int r = i0; r < R_DIM; r += stride) {
        unsigned long long key = keys[r];
        if ((unsigned)(key >> 48) >= B) {
            unsigned slot = atomicAdd(counter, 1u);
            if (slot < CAP) cand[slot] = key;
        }
    }
}

// K4: exact global rank (unchanged).
__global__ void __launch_bounds__(256) rank_emit_kernel(
    const unsigned long long* __restrict__ cand,
    const unsigned* __restrict__ counter,
    int* __restrict__ sel_idx, float* __restrict__ sel_scale) {
    unsigned n = *counter;
    if (n > CAP) n = CAP;
    unsigned s = blockIdx.x * blockDim.x + threadIdx.x;
    if (s >= n) return;
    unsigned long long k1 = cand[s];
    unsigned rank = 0;
    for (unsigned q = 0; q < n; q++) rank += (cand[q] > k1) ? 1u : 0u;
    if (rank < K_SEL) {
        unsigned idxv = ~(unsigned)(k1 & 0xFFFFFFFFull);
        sel_idx[rank]   = (int)idxv;
        sel_scale[rank] = tanhf(unsortable_key32((unsigned)(k1 >> 32)));
    }
}

// K5: materialize X[k][j] = embs[sel_idx[j]][k] * scale[j] (unchanged).
__global__ void __launch_bounds__(256) build_x_kernel(
    const float* __restrict__ embs, const int* __restrict__ sel_idx,
    const float* __restrict__ sel_scale, float* __restrict__ X) {
    const int j = blockIdx.x;
    const int row = sel_idx[j];
    const float sc = sel_scale[j];
    const int k = threadIdx.x;
    X[(size_t)k * O_DIM + j] = embs[(size_t)row * I_DIM + k] * sc;
}

// ==== GRU gates v5: global_load_lds-staged streams + s_load weights ====
// Evidence: rounds 1 & 4 prove hipcc serializes per-thread global streams
// (collapses any C-level rotation; ~600cyc cross-XCD latency per load ->
// ~130us). Fix: 1-wave blocks; X/history k-chunks DMA'd to LDS (lane = j:
// stage coalesced 256B/instr, read conflict-free 2-way b32); weights on the
// scalar pipe (round-1 SGPR=112 proved s_load emission). TI=8 i-rows/thread:
// 40 FMA per k vs 2 LDS reads. FMA order k-ascending, operands verbatim ->
// bit-exact vs v4.
#define GTI 8
#define GKC 32

__global__ void __launch_bounds__(64) gate_ur_kernel(
    const float* __restrict__ X, const float* __restrict__ history,
    const float* __restrict__ Wu, const float* __restrict__ Uu,
    const float* __restrict__ bu,
    const float* __restrict__ Wr, const float* __restrict__ Ur,
    const float* __restrict__ br,
    const float* __restrict__ Wh,
    float* __restrict__ u_out, float* __restrict__ rh,
    float* __restrict__ wxh) {
    __shared__ __align__(16) float shx[GKC][64];
    __shared__ __align__(16) float shh[GKC][64];
    const int tid = threadIdx.x;
    const int j   = blockIdx.x * 64 + tid;
    const int i0  = blockIdx.y * GTI;

    const float* wu = Wu + (size_t)i0 * I_DIM;   // wave-uniform -> s_load
    const float* uu = Uu + (size_t)i0 * I_DIM;
    const float* wr = Wr + (size_t)i0 * I_DIM;
    const float* ur = Ur + (size_t)i0 * I_DIM;
    const float* wh = Wh + (size_t)i0 * I_DIM;

    float aUx[GTI], aUh[GTI], aRx[GTI], aRh[GTI], aHx[GTI];
    #pragma unroll
    for (int ii = 0; ii < GTI; ii++) {
        aUx[ii] = 0.f; aUh[ii] = 0.f; aRx[ii] = 0.f; aRh[ii] = 0.f; aHx[ii] = 0.f;
    }

    for (int m = 0; m < I_DIM / GKC; m++) {
        const int kbase = m * GKC;
        WAIT_LGKM0();                       // prior chunk's ds_reads landed
        #pragma unroll
        for (int kk = 0; kk < GKC; kk++) {
            gload_lds4(X       + (size_t)(kbase + kk) * O_DIM + j, &shx[kk][0]);
            gload_lds4(history + (size_t)(kbase + kk) * O_DIM + j, &shh[kk][0]);
        }
        WAIT_VM0();
        #pragma unroll 4
        for (int kk = 0; kk < GKC; kk++) {
            const float xv = shx[kk][tid];
            const float hv = shh[kk][tid];
            const int k = kbase + kk;
            #pragma unroll
            for (int ii = 0; ii < GTI; ii++) {
                aUx[ii] = fmaf(wu[ii * I_DIM + k], xv, aUx[ii]);
                aUh[ii] = fmaf(uu[ii * I_DIM + k], hv, aUh[ii]);
                aRx[ii] = fmaf(wr[ii * I_DIM + k], xv, aRx[ii]);
                aRh[ii] = fmaf(ur[ii * I_DIM + k], hv, aRh[ii]);
                aHx[ii] = fmaf(wh[ii * I_DIM + k], xv, aHx[ii]);
            }
        }
    }

    #pragma unroll
    for (int ii = 0; ii < GTI; ii++) {
        const size_t o = (size_t)(i0 + ii) * O_DIM + j;
        float uz = aUx[ii] + aUh[ii] + bu[o];
        float rz = aRx[ii] + aRh[ii] + br[o];
        float ug = 1.f / (1.f + expf(-uz));
        float rg = 1.f / (1.f + expf(-rz));
        u_out[o] = ug;
        rh[o]    = rg * history[o];
        wxh[o]   = aHx[ii];
    }
}

__global__ void __launch_bounds__(64) gate_h_kernel(
    const float* __restrict__ history, const float* __restrict__ Uh,
    const float* __restrict__ bh,
    const float* __restrict__ u_out, const float* __restrict__ rh,
    const float* __restrict__ wxh, float* __restrict__ out) {
    __shared__ __align__(16) float shr[GKC][64];
    const int tid = threadIdx.x;
    const int j   = blockIdx.x * 64 + tid;
    const int i0  = blockIdx.y * GTI;

    const float* uh = Uh + (size_t)i0 * I_DIM;

    float acc[GTI];
    #pragma unroll
    for (int ii = 0; ii < GTI; ii++) acc[ii] = 0.f;

    for (int m = 0; m < I_DIM / GKC; m++) {
        const int kbase = m * GKC;
        WAIT_LGKM0();
        #pragma unroll
        for (int kk = 0; kk < GKC; kk++)
            gload_lds4(rh + (size_t)(kbase + kk) * O_DIM + j, &shr[kk][0]);
        WAIT_VM0();
        #pragma unroll 4
        for (int kk = 0; kk < GKC; kk++) {
            const float rv = shr[kk][tid];
            const int k = kbase + kk;
            #pragma unroll
            for (int ii = 0; ii < GTI; ii++)
                acc[ii] = fmaf(uh[ii * I_DIM + k], rv, acc[ii]);
        }
    }

    #pragma unroll
    for (int ii = 0; ii < GTI; ii++) {
        const size_t o = (size_t)(i0 + ii) * O_DIM + j;
        float hcap = tanhf(wxh[o] + acc[ii] + bh[o]);
        float ug = u_out[o];
        out[o] = (1.f - ug) * history[o] + ug * hcap;
    }
}

extern "C" void kernel_launch(void* const* d_in, const int* in_sizes, int n_in,
                              void* d_out, int out_size, void* d_ws, size_t ws_size,
                              hipStream_t stream) {
    const float* embs    = (const float*)d_in[0];
    const float* history = (const float*)d_in[1];
    const float* mask    = (const float*)d_in[2];
    const float* p       = (const float*)d_in[3];
    const float* Wu      = (const float*)d_in[4];
    const float* Uu      = (const float*)d_in[5];
    const float* bu      = (const float*)d_in[6];
    const float* Wr      = (const float*)d_in[7];
    const float* Ur      = (const float*)d_in[8];
    const float* br      = (const float*)d_in[9];
    const float* Wh      = (const float*)d_in[10];
    const float* Uh      = (const float*)d_in[11];
    const float* bh      = (const float*)d_in[12];
    float* out = (float*)d_out;

    unsigned* ws = (unsigned*)d_ws;
    unsigned* hist = ws + WS_HIST;
    unsigned* meta = ws + WS_META;
    unsigned long long* cand = (unsigned long long*)(ws + WS_CAND);
    int* sel_idx     = (int*)(ws + WS_IDX);
    float* sel_scale = (float*)(ws + WS_SCALE);
    unsigned long long* keys = (unsigned long long*)(ws + WS_KEYS);
    float* rh  = (float*)(ws + WS_RH);
    float* wxh = (float*)(ws + WS_WXH);
    float* X   = (float*)(ws + WS_X);
    float* normp = (float*)(meta + 4);

    hipMemsetAsync(ws, 0, (size_t)(WS_META + 16) * sizeof(unsigned), stream);

    hipLaunchKernelGGL(norm_kernel, dim3(1), dim3(64), 0, stream, p, normp);
    hipLaunchKernelGGL(score_hist_kernel, dim3((R_DIM + 255) / 256), dim3(256), 0, stream,
                       embs, p, mask, normp, keys, hist);
    hipLaunchKernelGGL(find_thresh_kernel, dim3(1), dim3(1024), 0, stream,
                       hist, meta);
    hipLaunchKernelGGL(compact_kernel, dim3(512), dim3(256), 0, stream,
                       keys, meta, meta + 2, cand);
    hipLaunchKernelGGL(rank_emit_kernel, dim3(CAP / 256), dim3(256), 0, stream,
                       cand, meta + 2, sel_idx, sel_scale);
    hipLaunchKernelGGL(build_x_kernel, dim3(K_SEL), dim3(256), 0, stream,
                       embs, sel_idx, sel_scale, X);
    hipLaunchKernelGGL(gate_ur_kernel, dim3(O_DIM / 64, I_DIM / GTI), dim3(64), 0, stream,
                       X, history, Wu, Uu, bu, Wr, Ur, br, Wh,
                       out /*u*/, rh, wxh);
    hipLaunchKernelGGL(gate_h_kernel, dim3(O_DIM / 64, I_DIM / GTI), dim3(64), 0, stream,
                       history, Uh, bh, out /*u*/, rh, wxh, out);
}

// Round 6
// 536.125 us; speedup vs baseline: 1.3685x; 1.1841x over previous
//
#include <hip/hip_runtime.h>
#include <math.h>

#define I_DIM 256
#define O_DIM 2048
#define R_DIM 200000
#define K_SEL 2048
#define CAP   8192

// ---- workspace layout (offsets in u32 units) ----
#define WS_HIST   0         // u32[65536]
#define WS_META   65536     // u32[16]: [0]=B, [1]=tot, [2]=counter, [4]=norm f32
#define WS_CAND   65552     // u64[CAP] (16384 u32)
#define WS_IDX    81936     // i32[2048]
#define WS_SCALE  83984     // f32[2048]
#define WS_KEYS   86032     // u64[R] (400000 u32)
#define WS_RH     486032    // f32[I*O] (524288 u32)
#define WS_WXH    1010320   // f32[I*O] (524288 u32)
#define WS_X      1534608   // f32[I*O] (524288 u32)  x_topk in [k][j] layout

typedef unsigned int u32;
typedef __attribute__((address_space(1))) u32 gu32;
typedef __attribute__((address_space(3))) u32 lu32;

// Direct HBM->LDS DMA (validated path, guide §5): no VGPR staging, vmcnt-tracked.
// LDS dest = wave-uniform base + lane*16; global source is per-lane.
static __device__ __forceinline__ void gload_lds16(const float* g, float* l) {
    __builtin_amdgcn_global_load_lds((const gu32*)g, (lu32*)l, 16, 0, 0);
}

__device__ __forceinline__ unsigned sortable_key32(float f) {
    unsigned b = __float_as_uint(f);
    return (b & 0x80000000u) ? ~b : (b | 0x80000000u);
}
__device__ __forceinline__ float unsortable_key32(unsigned k) {
    unsigned b = (k & 0x80000000u) ? (k ^ 0x80000000u) : ~k;
    return __uint_as_float(b);
}

// K0: norm = fl32(sqrt(exact sum p^2)).
__global__ void norm_kernel(const float* __restrict__ p, float* __restrict__ norm_out) {
    if (threadIdx.x == 0) {
        double n = 0.0;
        for (int k = 0; k < I_DIM; k++) { double v = (double)p[k]; n += v * v; }
        norm_out[0] = (float)sqrt(n);
    }
}

// K1 v5: v4's validated swizzle/compute mapping + COUNTED-vmcnt double buffer
// (v4's per-chunk vmcnt(0) drain exposed full HBM latency each chunk). 1-wave
// blocks (R%64==0 -> no edge divergence), tile[2][64][32]=16KB+sp=17KB ->
// 9 blocks/CU; each wave keeps >=8KB outstanding continuously via vmcnt(8).
// FMA order & operands identical to the passing v4 -> bit-exact.
__global__ void __launch_bounds__(64) score_hist_kernel(
    const float* __restrict__ embs, const float* __restrict__ p,
    const float* __restrict__ mask, const float* __restrict__ normp,
    unsigned long long* __restrict__ keys, unsigned* __restrict__ hist) {
    __shared__ __align__(16) float sp[I_DIM];
    __shared__ __align__(16) float tile[2][64][32];   // 16KB double buffer
    const int lane = threadIdx.x;
    #pragma unroll
    for (int t = 0; t < 4; t++) sp[lane + 64 * t] = p[lane + 64 * t];
    __syncthreads();

    const int row0 = blockIdx.x * 64;
    const int r    = row0 + lane;                       // 3125*64 == R_DIM exactly
    const int c4   = (lane & 7) ^ (lane >> 3);          // source-side swizzle
    const int rsub = lane >> 3;                         // row within 8-row group

    float L[8] = {0.f,0.f,0.f,0.f,0.f,0.f,0.f,0.f};

    // prologue: stage chunk 0 into buf 0 (8 instr, 1KB each: 8 rows x 128B)
    #pragma unroll
    for (int a = 0; a < 8; a++)
        gload_lds16(embs + (size_t)(row0 + 8 * a + rsub) * I_DIM + c4 * 4,
                    &tile[0][a * 8][0]);

    for (int m = 0; m < 7; m++) {
        // stage chunk m+1 into the other buffer (outstanding rises to 16)
        #pragma unroll
        for (int a = 0; a < 8; a++)
            gload_lds16(embs + (size_t)(row0 + 8 * a + rsub) * I_DIM
                             + (m + 1) * 32 + c4 * 4,
                        &tile[(m + 1) & 1][a * 8][0]);
        asm volatile("s_waitcnt vmcnt(8)" ::: "memory");   // chunk m landed
        __builtin_amdgcn_sched_barrier(0);
        #pragma unroll
        for (int i4 = 0; i4 < 8; i4++) {
            const int slot = i4 ^ (lane & 7);              // read-side swizzle
            float4 a4 = *(const float4*)&tile[m & 1][lane][slot * 4];
            float4 q  = *(const float4*)&sp[m * 32 + i4 * 4];
            const int base = (4 * i4) & 7;                 // 0 or 4
            L[base + 0] = fmaf(a4.x, q.x, L[base + 0]);
            L[base + 1] = fmaf(a4.y, q.y, L[base + 1]);
            L[base + 2] = fmaf(a4.z, q.z, L[base + 2]);
            L[base + 3] = fmaf(a4.w, q.w, L[base + 3]);
        }
    }
    asm volatile("s_waitcnt vmcnt(0)" ::: "memory");       // final chunk
    __builtin_amdgcn_sched_barrier(0);
    #pragma unroll
    for (int i4 = 0; i4 < 8; i4++) {
        const int slot = i4 ^ (lane & 7);
        float4 a4 = *(const float4*)&tile[1][lane][slot * 4];
        float4 q  = *(const float4*)&sp[7 * 32 + i4 * 4];
        const int base = (4 * i4) & 7;
        L[base + 0] = fmaf(a4.x, q.x, L[base + 0]);
        L[base + 1] = fmaf(a4.y, q.y, L[base + 1]);
        L[base + 2] = fmaf(a4.z, q.z, L[base + 2]);
        L[base + 3] = fmaf(a4.w, q.w, L[base + 3]);
    }

    float t0 = L[0] + L[4], t1 = L[1] + L[5], t2 = L[2] + L[6], t3 = L[3] + L[7];
    float d = (t0 + t1) + (t2 + t3);
    float s = d / normp[0] + mask[r];
    unsigned k32 = sortable_key32(s);
    keys[r] = ((unsigned long long)k32 << 32) |
              (unsigned long long)(~(unsigned)r);   // lower idx wins ties
    atomicAdd(&hist[k32 >> 16], 1u);
}

// K2: find threshold bin B (unchanged).
__global__ void __launch_bounds__(1024) find_thresh_kernel(
    const unsigned* __restrict__ hist, unsigned* __restrict__ meta) {
    __shared__ unsigned T[1024];
    const int t = threadIdx.x;
    const int base = t * 64;
    unsigned s = 0;
    for (int b = 0; b < 64; b++) s += hist[base + b];
    T[t] = s;
    __syncthreads();
    if (t == 0) {
        unsigned run = 0;
        int chunk = 1023;
        while (chunk >= 0 && run + T[chunk] < K_SEL) { run += T[chunk]; chunk--; }
        unsigned B = 0, tot = run;
        if (chunk >= 0) {
            unsigned r2 = run;
            for (int b = 63; b >= 0; b--) {
                unsigned c = hist[chunk * 64 + b];
                if (r2 + c >= K_SEL) { B = (unsigned)(chunk * 64 + b); tot = r2 + c; break; }
                r2 += c;
            }
        }
        meta[0] = B;
        meta[1] = tot;
    }
}

// K3: compact keys with bin >= B (unchanged).
__global__ void __launch_bounds__(256) compact_kernel(
    const unsigned long long* __restrict__ keys,
    const unsigned* __restrict__ meta, unsigned* __restrict__ counter,
    unsigned long long* __restrict__ cand) {
    const unsigned B = meta[0];
    int i0 = blockIdx.x * blockDim.x + threadIdx.x;
    int stride = gridDim.x * blockDim.x;
    for (int r = i0; r < R_DIM; r += stride) {
        unsigned long long key = keys[r];
        if ((unsigned)(key >> 48) >= B) {
            unsigned slot = atomicAdd(counter, 1u);
            if (slot < CAP) cand[slot] = key;
        }
    }
}

// K4: exact global rank (unchanged).
__global__ void __launch_bounds__(256) rank_emit_kernel(
    const unsigned long long* __restrict__ cand,
    const unsigned* __restrict__ counter,
    int* __restrict__ sel_idx, float* __restrict__ sel_scale) {
    unsigned n = *counter;
    if (n > CAP) n = CAP;
    unsigned s = blockIdx.x * blockDim.x + threadIdx.x;
    if (s >= n) return;
    unsigned long long k1 = cand[s];
    unsigned rank = 0;
    for (unsigned q = 0; q < n; q++) rank += (cand[q] > k1) ? 1u : 0u;
    if (rank < K_SEL) {
        unsigned idxv = ~(unsigned)(k1 & 0xFFFFFFFFull);
        sel_idx[rank]   = (int)idxv;
        sel_scale[rank] = tanhf(unsortable_key32((unsigned)(k1 >> 32)));
    }
}

// K5: materialize X[k][j] = embs[sel_idx[j]][k] * scale[j] (unchanged).
__global__ void __launch_bounds__(256) build_x_kernel(
    const float* __restrict__ embs, const int* __restrict__ sel_idx,
    const float* __restrict__ sel_scale, float* __restrict__ X) {
    const int j = blockIdx.x;
    const int row = sel_idx[j];
    const float sc = sel_scale[j];
    const int k = threadIdx.x;
    X[(size_t)k * O_DIM + j] = embs[(size_t)row * I_DIM + k] * sc;
}

// ==== GRU gates v6: LDS-tiled GEMM, everything staged via global_load_lds ====
// Lessons encoded: per-thread global streams serialize (r1/r4); LDS-broadcast
// per-k inner loops are LDS-pipe-bound (r2); s_load-operand inner loops at 1
// wave/SIMD stall on scalar cache (r5). v6 = the m97-style pattern: cooperative
// DMA staging of ALL operands, conflict-free ds_read_b128 consumption, 20 FMA
// per thread per k vs ~3 LDS reads. 512 blocks (2/CU), 256 threads (4 waves).
// Weight tiles XOR-swizzled source+read (both-sides rule) -> conflict-free.
// FMA chains per accumulator stay k-ascending with identical operand values ->
// bit-exact vs all prior passing versions.
#define UR_JT 64
#define UR_IT 16
#define UR_KC 32

__global__ void __launch_bounds__(256) gate_ur_kernel(
    const float* __restrict__ X, const float* __restrict__ history,
    const float* __restrict__ Wu, const float* __restrict__ Uu,
    const float* __restrict__ bu,
    const float* __restrict__ Wr, const float* __restrict__ Ur,
    const float* __restrict__ br,
    const float* __restrict__ Wh,
    float* __restrict__ u_out, float* __restrict__ rh,
    float* __restrict__ wxh) {
    __shared__ __align__(16) float sx[UR_KC][UR_JT];        // 8KB
    __shared__ __align__(16) float sh[UR_KC][UR_JT];        // 8KB
    __shared__ __align__(16) float swt[5][UR_IT][UR_KC];    // 10KB
    const int tid  = threadIdx.x;
    const int w    = tid >> 6;          // wave id 0..3
    const int lane = tid & 63;
    const int j4   = tid & 15;          // j-group (4 consecutive j)
    const int il   = tid >> 4;          // local i row 0..15
    const int jb   = blockIdx.x * UR_JT;
    const int i0   = blockIdx.y * UR_IT;
    const float* mats[5] = {Wu, Uu, Wr, Ur, Wh};

    float acc[5][4];
    #pragma unroll
    for (int m = 0; m < 5; m++)
        #pragma unroll
        for (int jj = 0; jj < 4; jj++) acc[m][jj] = 0.f;

    for (int kb = 0; kb < I_DIM; kb += UR_KC) {
        // ---- stage: wave-partitioned DMA (each instr: 64 lanes x 16B = 1KB)
        // sx/sh instr a covers k-rows 4a..4a+3 (lane: kl=4a+(l>>4), jc=l&15)
        #pragma unroll
        for (int a = 0; a < 8; a++) {
            if ((a & 3) == w) {
                const size_t krow = (size_t)(kb + 4 * a + (lane >> 4));
                gload_lds16(X       + krow * O_DIM + jb + (lane & 15) * 4, &sx[4 * a][0]);
                gload_lds16(history + krow * O_DIM + jb + (lane & 15) * 4, &sh[4 * a][0]);
            }
        }
        // weights: instr s=(m,b) covers rows 8b..8b+7 of mat m; source chunk
        // pre-swizzled (cc = c ^ row&7) so linear LDS + swizzled read pair up.
        #pragma unroll
        for (int s = 0; s < 10; s++) {
            if ((s & 3) == w) {
                const int m  = s >> 1, b = s & 1;
                const int rl = 8 * b + (lane >> 3);
                const int cc = (lane & 7) ^ (lane >> 3);
                gload_lds16(mats[m] + (size_t)(i0 + rl) * I_DIM + kb + cc * 4,
                            &swt[m][8 * b][0]);
            }
        }
        asm volatile("s_waitcnt vmcnt(0)" ::: "memory");
        __builtin_amdgcn_sched_barrier(0);
        __syncthreads();
        // ---- compute: per k4: 5 swizzled w-reads (b128) + 8 x/h reads, 80 FMA
        #pragma unroll
        for (int k4 = 0; k4 < 8; k4++) {
            float4 wv[5];
            #pragma unroll
            for (int m = 0; m < 5; m++)
                wv[m] = *(const float4*)&swt[m][il][(k4 ^ (il & 7)) << 2];
            #pragma unroll
            for (int t = 0; t < 4; t++) {
                const int kk = (k4 << 2) + t;
                float4 x4 = *(const float4*)&sx[kk][j4 << 2];
                float4 h4 = *(const float4*)&sh[kk][j4 << 2];
                const float wuv = ((const float*)&wv[0])[t];
                const float uuv = ((const float*)&wv[1])[t];
                const float wrv = ((const float*)&wv[2])[t];
                const float urv = ((const float*)&wv[3])[t];
                const float whv = ((const float*)&wv[4])[t];
                acc[0][0] = fmaf(wuv, x4.x, acc[0][0]);
                acc[0][1] = fmaf(wuv, x4.y, acc[0][1]);
                acc[0][2] = fmaf(wuv, x4.z, acc[0][2]);
                acc[0][3] = fmaf(wuv, x4.w, acc[0][3]);
                acc[1][0] = fmaf(uuv, h4.x, acc[1][0]);
                acc[1][1] = fmaf(uuv, h4.y, acc[1][1]);
                acc[1][2] = fmaf(uuv, h4.z, acc[1][2]);
                acc[1][3] = fmaf(uuv, h4.w, acc[1][3]);
                acc[2][0] = fmaf(wrv, x4.x, acc[2][0]);
                acc[2][1] = fmaf(wrv, x4.y, acc[2][1]);
                acc[2][2] = fmaf(wrv, x4.z, acc[2][2]);
                acc[2][3] = fmaf(wrv, x4.w, acc[2][3]);
                acc[3][0] = fmaf(urv, h4.x, acc[3][0]);
                acc[3][1] = fmaf(urv, h4.y, acc[3][1]);
                acc[3][2] = fmaf(urv, h4.z, acc[3][2]);
                acc[3][3] = fmaf(urv, h4.w, acc[3][3]);
                acc[4][0] = fmaf(whv, x4.x, acc[4][0]);
                acc[4][1] = fmaf(whv, x4.y, acc[4][1]);
                acc[4][2] = fmaf(whv, x4.z, acc[4][2]);
                acc[4][3] = fmaf(whv, x4.w, acc[4][3]);
            }
        }
        __syncthreads();   // before next chunk overwrites the tiles
    }

    // epilogue: 4 consecutive j per thread -> float4 loads/stores
    const size_t o = (size_t)(i0 + il) * O_DIM + jb + (j4 << 2);
    float4 b_u = *(const float4*)(bu + o);
    float4 b_r = *(const float4*)(br + o);
    float4 hh  = *(const float4*)(history + o);
    float4 ug4, rh4, wx4;
    {
        float uz, rz, ug, rg;
        uz = acc[0][0] + acc[1][0] + b_u.x; rz = acc[2][0] + acc[3][0] + b_r.x;
        ug = 1.f / (1.f + expf(-uz)); rg = 1.f / (1.f + expf(-rz));
        ug4.x = ug; rh4.x = rg * hh.x; wx4.x = acc[4][0];
        uz = acc[0][1] + acc[1][1] + b_u.y; rz = acc[2][1] + acc[3][1] + b_r.y;
        ug = 1.f / (1.f + expf(-uz)); rg = 1.f / (1.f + expf(-rz));
        ug4.y = ug; rh4.y = rg * hh.y; wx4.y = acc[4][1];
        uz = acc[0][2] + acc[1][2] + b_u.z; rz = acc[2][2] + acc[3][2] + b_r.z;
        ug = 1.f / (1.f + expf(-uz)); rg = 1.f / (1.f + expf(-rz));
        ug4.z = ug; rh4.z = rg * hh.z; wx4.z = acc[4][2];
        uz = acc[0][3] + acc[1][3] + b_u.w; rz = acc[2][3] + acc[3][3] + b_r.w;
        ug = 1.f / (1.f + expf(-uz)); rg = 1.f / (1.f + expf(-rz));
        ug4.w = ug; rh4.w = rg * hh.w; wx4.w = acc[4][3];
    }
    *(float4*)(u_out + o) = ug4;
    *(float4*)(rh + o)    = rh4;
    *(float4*)(wxh + o)   = wx4;
}

// gate_h v6: same structure, 1 matrix, 2i x 4j per thread. 256 blocks (1/CU).
#define H_JT 64
#define H_IT 32
#define H_KC 32

__global__ void __launch_bounds__(256) gate_h_kernel(
    const float* __restrict__ history, const float* __restrict__ Uh,
    const float* __restrict__ bh,
    const float* __restrict__ u_out, const float* __restrict__ rh,
    const float* __restrict__ wxh, float* __restrict__ out) {
    __shared__ __align__(16) float sr[H_KC][H_JT];      // 8KB
    __shared__ __align__(16) float swt[H_IT][H_KC];     // 4KB
    const int tid  = threadIdx.x;
    const int w    = tid >> 6;
    const int lane = tid & 63;
    const int j4   = tid & 15;
    const int il0  = (tid >> 4) << 1;   // 2 consecutive local i rows
    const int jb   = blockIdx.x * H_JT;
    const int i0   = blockIdx.y * H_IT;

    float acc[2][4];
    #pragma unroll
    for (int ii = 0; ii < 2; ii++)
        #pragma unroll
        for (int jj = 0; jj < 4; jj++) acc[ii][jj] = 0.f;

    for (int kb = 0; kb < I_DIM; kb += H_KC) {
        #pragma unroll
        for (int a = 0; a < 8; a++) {
            if ((a & 3) == w)
                gload_lds16(rh + (size_t)(kb + 4 * a + (lane >> 4)) * O_DIM
                               + jb + (lane & 15) * 4, &sr[4 * a][0]);
        }
        #pragma unroll
        for (int b = 0; b < 4; b++) {
            if (b == w) {
                const int rl = 8 * b + (lane >> 3);
                const int cc = (lane & 7) ^ (lane >> 3);
                gload_lds16(Uh + (size_t)(i0 + rl) * I_DIM + kb + cc * 4,
                            &swt[8 * b][0]);
            }
        }
        asm volatile("s_waitcnt vmcnt(0)" ::: "memory");
        __builtin_amdgcn_sched_barrier(0);
        __syncthreads();
        #pragma unroll
        for (int k4 = 0; k4 < 8; k4++) {
            float4 wv0 = *(const float4*)&swt[il0][(k4 ^ (il0 & 7)) << 2];
            float4 wv1 = *(const float4*)&swt[il0 + 1][(k4 ^ ((il0 + 1) & 7)) << 2];
            #pragma unroll
            for (int t = 0; t < 4; t++) {
                const int kk = (k4 << 2) + t;
                float4 r4 = *(const float4*)&sr[kk][j4 << 2];
                const float w0 = ((const float*)&wv0)[t];
                const float w1 = ((const float*)&wv1)[t];
                acc[0][0] = fmaf(w0, r4.x, acc[0][0]);
                acc[0][1] = fmaf(w0, r4.y, acc[0][1]);
                acc[0][2] = fmaf(w0, r4.z, acc[0][2]);
                acc[0][3] = fmaf(w0, r4.w, acc[0][3]);
                acc[1][0] = fmaf(w1, r4.x, acc[1][0]);
                acc[1][1] = fmaf(w1, r4.y, acc[1][1]);
                acc[1][2] = fmaf(w1, r4.z, acc[1][2]);
                acc[1][3] = fmaf(w1, r4.w, acc[1][3]);
            }
        }
        __syncthreads();
    }

    #pragma unroll
    for (int ii = 0; ii < 2; ii++) {
        const size_t o = (size_t)(i0 + il0 + ii) * O_DIM + jb + (j4 << 2);
        float4 wx = *(const float4*)(wxh + o);
        float4 b4 = *(const float4*)(bh + o);
        float4 u4 = *(const float4*)(u_out + o);
        float4 hh = *(const float4*)(history + o);
        float4 o4;
        float hc;
        hc = tanhf(wx.x + acc[ii][0] + b4.x); o4.x = (1.f - u4.x) * hh.x + u4.x * hc;
        hc = tanhf(wx.y + acc[ii][1] + b4.y); o4.y = (1.f - u4.y) * hh.y + u4.y * hc;
        hc = tanhf(wx.z + acc[ii][2] + b4.z); o4.z = (1.f - u4.z) * hh.z + u4.z * hc;
        hc = tanhf(wx.w + acc[ii][3] + b4.w); o4.w = (1.f - u4.w) * hh.w + u4.w * hc;
        *(float4*)(out + o) = o4;
    }
}

extern "C" void kernel_launch(void* const* d_in, const int* in_sizes, int n_in,
                              void* d_out, int out_size, void* d_ws, size_t ws_size,
                              hipStream_t stream) {
    const float* embs    = (const float*)d_in[0];
    const float* history = (const float*)d_in[1];
    const float* mask    = (const float*)d_in[2];
    const float* p       = (const float*)d_in[3];
    const float* Wu      = (const float*)d_in[4];
    const float* Uu      = (const float*)d_in[5];
    const float* bu      = (const float*)d_in[6];
    const float* Wr      = (const float*)d_in[7];
    const float* Ur      = (const float*)d_in[8];
    const float* br      = (const float*)d_in[9];
    const float* Wh      = (const float*)d_in[10];
    const float* Uh      = (const float*)d_in[11];
    const float* bh      = (const float*)d_in[12];
    float* out = (float*)d_out;

    unsigned* ws = (unsigned*)d_ws;
    unsigned* hist = ws + WS_HIST;
    unsigned* meta = ws + WS_META;
    unsigned long long* cand = (unsigned long long*)(ws + WS_CAND);
    int* sel_idx     = (int*)(ws + WS_IDX);
    float* sel_scale = (float*)(ws + WS_SCALE);
    unsigned long long* keys = (unsigned long long*)(ws + WS_KEYS);
    float* rh  = (float*)(ws + WS_RH);
    float* wxh = (float*)(ws + WS_WXH);
    float* X   = (float*)(ws + WS_X);
    float* normp = (float*)(meta + 4);

    hipMemsetAsync(ws, 0, (size_t)(WS_META + 16) * sizeof(unsigned), stream);

    hipLaunchKernelGGL(norm_kernel, dim3(1), dim3(64), 0, stream, p, normp);
    hipLaunchKernelGGL(score_hist_kernel, dim3(R_DIM / 64), dim3(64), 0, stream,
                       embs, p, mask, normp, keys, hist);
    hipLaunchKernelGGL(find_thresh_kernel, dim3(1), dim3(1024), 0, stream,
                       hist, meta);
    hipLaunchKernelGGL(compact_kernel, dim3(512), dim3(256), 0, stream,
                       keys, meta, meta + 2, cand);
    hipLaunchKernelGGL(rank_emit_kernel, dim3(CAP / 256), dim3(256), 0, stream,
                       cand, meta + 2, sel_idx, sel_scale);
    hipLaunchKernelGGL(build_x_kernel, dim3(K_SEL), dim3(256), 0, stream,
                       embs, sel_idx, sel_scale, X);
    hipLaunchKernelGGL(gate_ur_kernel, dim3(O_DIM / UR_JT, I_DIM / UR_IT), dim3(256), 0, stream,
                       X, history, Wu, Uu, bu, Wr, Ur, br, Wh,
                       out /*u*/, rh, wxh);
    hipLaunchKernelGGL(gate_h_kernel, dim3(O_DIM / H_JT, I_DIM / H_IT), dim3(256), 0, stream,
                       history, Uh, bh, out /*u*/, rh, wxh, out);
}